// Round 6
// baseline (133.178 us; speedup 1.0000x reference)
//
#include <hip/hip_runtime.h>

// LIF integrate-fire-reset scan over T.
// inputs: [B=32, T=2048, N=1024] f32; thresh: [N] f32; out: [B, T, N] f32.
//
// One thread per PAIR of (b, n) chains (native-vector float2 over adjacent n):
//   16384 threads = 256 waves = 1 wave/CU, 512 B contiguous per wave-load.
// Sequential-in-T scan; parallel over B*N. Memory-bound: 537 MB total
// traffic, ~85 us at the 6.3 TB/s mixed-stream ceiling.
//
// Latency hiding via A/B register ping-pong (NO rotation copies): loads for
// buffer B are issued before computing buffer A, so every chunk's loads have
// a full chunk of compute to land, and no end-of-iteration vmcnt drain is
// forced by register moves.
// In flight: 32 loads x 8 B x 16384 threads = 4 MB > ~2.5 MB BW*latency.
//
// NOTE: HIP's float2 is HIP_vector_type (a class) — rejected by
// __builtin_nontemporal_*; use a clang ext_vector_type instead.

typedef float f32x2 __attribute__((ext_vector_type(2)));

constexpr int T_STEPS = 2048;
constexpr int N_COLS  = 1024;
constexpr int U       = 32;              // timesteps per buffer
constexpr int STRIDE2 = N_COLS / 2;      // row stride in f32x2 units

__global__ __launch_bounds__(64, 1)
void lif_scan_kernel(const f32x2* __restrict__ x,
                     const float* __restrict__ thresh,
                     f32x2*       __restrict__ out)
{
    const int gid = blockIdx.x * blockDim.x + threadIdx.x;  // 0 .. B*N/2-1
    const int b   = gid >> 9;                 // / STRIDE2
    const int n2  = gid & (STRIDE2 - 1);      // % STRIDE2

    const float thx = thresh[2 * n2];
    const float thy = thresh[2 * n2 + 1];

    const size_t base = (size_t)b * T_STEPS * STRIDE2 + n2;
    const f32x2* __restrict__ p = x   + base;
    f32x2*       __restrict__ q = out + base;

    f32x2 bufA[U];
    f32x2 bufB[U];

    float accx = 0.0f, accy = 0.0f;

    // ---- helpers (fully unrolled, static indices only) ----
#define LIF_LOAD(BUF, T0)                                                  \
    _Pragma("unroll")                                                      \
    for (int i = 0; i < U; ++i)                                            \
        BUF[i] = __builtin_nontemporal_load(&p[(size_t)((T0) + i) * STRIDE2]);

#define LIF_COMP(BUF, T0)                                                  \
    _Pragma("unroll")                                                      \
    for (int i = 0; i < U; ++i) {                                          \
        f32x2 v = BUF[i];                                                  \
        accx += v.x;                                                       \
        accy += v.y;                                                       \
        f32x2 o;                                                           \
        o.x = (accx > thx) ? accx : 0.0f;                                  \
        o.y = (accy > thy) ? accy : 0.0f;                                  \
        accx -= o.x;                                                       \
        accy -= o.y;                                                       \
        __builtin_nontemporal_store(o, &q[(size_t)((T0) + i) * STRIDE2]);  \
    }

    // prologue
    LIF_LOAD(bufA, 0);

    // steady state: ping-pong, always one chunk of loads in flight
    int t0 = 0;
    for (; t0 < T_STEPS - 2 * U; t0 += 2 * U) {
        LIF_LOAD(bufB, t0 + U);
        LIF_COMP(bufA, t0);
        LIF_LOAD(bufA, t0 + 2 * U);
        LIF_COMP(bufB, t0 + U);
    }

    // tail: t0 == T_STEPS - 2U here
    LIF_LOAD(bufB, t0 + U);
    LIF_COMP(bufA, t0);
    LIF_COMP(bufB, t0 + U);

#undef LIF_LOAD
#undef LIF_COMP
}

extern "C" void kernel_launch(void* const* d_in, const int* in_sizes, int n_in,
                              void* d_out, int out_size, void* d_ws, size_t ws_size,
                              hipStream_t stream)
{
    const f32x2* x      = (const f32x2*)d_in[0];
    const float* thresh = (const float*)d_in[1];
    f32x2*       out    = (f32x2*)d_out;

    const int chains2 = in_sizes[0] / T_STEPS / 2;   // B * N / 2 threads
    (void)out_size; (void)d_ws; (void)ws_size; (void)n_in;

    const int block = 64;
    const int grid  = (chains2 + block - 1) / block; // 256 blocks

    hipLaunchKernelGGL(lif_scan_kernel, dim3(grid), dim3(block), 0, stream,
                       x, thresh, out);
}

// Round 7
// 105.711 us; speedup vs baseline: 1.2598x; 1.2598x over previous
//
#include <hip/hip_runtime.h>

// LIF integrate-fire-reset scan over T.
// inputs: [B=32, T=2048, N=1024] f32; thresh: [N] f32; out: [B, T, N] f32.
//
// One thread per (b, n) chain, scalar f32: 32768 threads = 512 waves =
// 2 waves/CU (the max this problem's chain-parallelism allows). Coalesced:
// consecutive lanes -> consecutive n -> one contiguous 256 B segment per
// wave per timestep.
//
// Latency hiding via an IN-PLACE circular register pipeline of depth D:
//   use buf[i]  ->  buf[i] = load(t + D + i)
// No rotation copies (R4's flaw: end-of-chunk vmcnt drain + 32 movs), no
// ping-pong (R5's flaw: >63 younger vmem ops exceeded the 6-bit vmcnt
// field, and float2 halved occupancy to 1 wave/CU). Loads and stores issue
// evenly, 1+1 per element; each load has D elements of compute before use.
// Steady-state in flight: ~(32 loads + 32 stores) x 256 B x 512 waves ~ 8 MB.

constexpr int T_STEPS = 2048;
constexpr int N_COLS  = 1024;
constexpr int D       = 32;   // pipeline depth (T_STEPS % D == 0)

__global__ __launch_bounds__(64, 1)
void lif_scan_kernel(const float* __restrict__ x,
                     const float* __restrict__ thresh,
                     float* __restrict__ out)
{
    const int gid = blockIdx.x * blockDim.x + threadIdx.x;   // 0 .. B*N-1
    const int b   = gid >> 10;          // / N_COLS
    const int n   = gid & (N_COLS - 1); // % N_COLS

    const float thr = thresh[n];

    const size_t base = (size_t)b * T_STEPS * N_COLS + n;
    const float* __restrict__ p = x   + base;
    float*       __restrict__ q = out + base;

    float buf[D];

    // prologue: prime the pipeline
#pragma unroll
    for (int i = 0; i < D; ++i)
        buf[i] = __builtin_nontemporal_load(&p[(size_t)i * N_COLS]);

    float acc = 0.0f;

    // steady state: per element, consume slot i then refill it D ahead.
    for (int t0 = 0; t0 < T_STEPS - D; t0 += D) {
#pragma unroll
        for (int i = 0; i < D; ++i) {
            const float v = buf[i];
            buf[i] = __builtin_nontemporal_load(&p[(size_t)(t0 + D + i) * N_COLS]);
            acc += v;
            const float o = (acc > thr) ? acc : 0.0f;
            acc -= o;   // reset fired neuron to 0
            __builtin_nontemporal_store(o, &q[(size_t)(t0 + i) * N_COLS]);
        }
    }

    // epilogue: drain the last D elements (no further loads)
#pragma unroll
    for (int i = 0; i < D; ++i) {
        acc += buf[i];
        const float o = (acc > thr) ? acc : 0.0f;
        acc -= o;
        __builtin_nontemporal_store(o, &q[(size_t)(T_STEPS - D + i) * N_COLS]);
    }
}

extern "C" void kernel_launch(void* const* d_in, const int* in_sizes, int n_in,
                              void* d_out, int out_size, void* d_ws, size_t ws_size,
                              hipStream_t stream)
{
    const float* x      = (const float*)d_in[0];
    const float* thresh = (const float*)d_in[1];
    float*       out    = (float*)d_out;

    const int total = in_sizes[0] / T_STEPS;   // B * N chains
    (void)out_size; (void)d_ws; (void)ws_size; (void)n_in;

    const int block = 64;
    const int grid  = (total + block - 1) / block;   // 512 blocks

    hipLaunchKernelGGL(lif_scan_kernel, dim3(grid), dim3(block), 0, stream,
                       x, thresh, out);
}